// Round 13
// baseline (241.058 us; speedup 1.0000x reference)
//
#include <hip/hip_runtime.h>
#include <stdint.h>

typedef unsigned short u16;
typedef unsigned int u32;
typedef __attribute__((ext_vector_type(8))) short short8;
typedef __attribute__((ext_vector_type(4))) float f32x4;

#define L_IN   1323000
#define PAD    1024
#define HOP    441
#define T_FR   3001         // output rows (q) per (b,c)
#define M_ROWS 24008        // 8 * 3001
#define NBE    3016         // extended xb rows per bc: 4 zero | 3005 real | 7 zero
#define RPAD   448          // row length (441 padded to 448)
#define K1E    2240         // frame window length (5*448) in blocked coords
#define KC     4032         // composite K = 9*448
#define W_2PI_N 3.0679615757712823e-3f   // 2*pi/2048

__device__ __forceinline__ u16 f2bf(float f) {
  union { float f; u32 u; } v; v.f = f;
  u32 r = v.u + 0x7FFFu + ((v.u >> 16) & 1u);   // RNE
  return (u16)(r >> 16);
}
__device__ __forceinline__ float bf2f(u16 s) {
  union { u32 u; float f; } v; v.u = ((u32)s) << 16;
  return v.f;
}
__device__ __forceinline__ void gload16(const void* g, void* l) {
  __builtin_amdgcn_global_load_lds(
      (const __attribute__((address_space(1))) u32*)g,
      (__attribute__((address_space(3))) u32*)l, 16, 0, 0);
}

// ---------------- prep: extended bf16 x, weight layouts ----------------
// xbe[bc,u,r]: u<4 or u>3008 -> 0; else bf16(x_reflect[441(u-4)+r-1024])
// wh2 [m][k1=448j+r] = bf16(hann[441j+r]*W_enc[m,441j+r])   (0 if r>=441 or n>=2048)
// wh2t[k1][m]        = same, transposed
// b2  [r][512j+m]    = bf16(W_dec[441j+r,m] / win_norm_full(r))
__global__ void prep_all(const float* __restrict__ x,
                         const float* __restrict__ W_enc, const float* __restrict__ W_dec,
                         u16* __restrict__ xbe, u16* __restrict__ wh2,
                         u16* __restrict__ wh2t, u16* __restrict__ b2) {
  int stride = gridDim.x * blockDim.x;
  int tid0 = blockIdx.x * blockDim.x + threadIdx.x;
  for (int idx = tid0; idx < 8 * NBE * RPAD; idx += stride) {
    int bc = idx / (NBE * RPAD);
    int rem = idx - bc * (NBE * RPAD);
    int u = rem / RPAD;
    int r = rem - u * RPAD;
    u16 v = 0;
    if (u >= 4 && u <= 3008) {
      int s = HOP * (u - 4) + r - PAD;
      int ja = s < 0 ? -s : s;
      int jb = 2 * L_IN - 2 - ja;
      int jr = ja < jb ? ja : jb;        // reflect (no edge repeat)
      v = f2bf(x[(size_t)bc * L_IN + jr]);
    }
    xbe[idx] = v;
  }
  for (int idx = tid0; idx < 512 * K1E; idx += stride) {
    int m = idx / K1E;
    int k = idx - m * K1E;
    int j = k / RPAD;
    int r = k - j * RPAD;
    int n = HOP * j + r;
    float v = 0.f;
    if (r < HOP && n < 2048)
      v = (0.5f - 0.5f * cosf(W_2PI_N * (float)n)) * W_enc[m * 2048 + n];
    u16 b = f2bf(v);
    wh2[idx] = b;
    wh2t[k * 512 + m] = b;
  }
  for (int idx = tid0; idx < 512 * 2560; idx += stride) {
    int r = idx / 2560;
    int k = idx - r * 2560;
    int j = k >> 9;
    int m = k & 511;
    int n = HOP * j + r;
    float v = 0.f;
    if (r < HOP && n < 2048) {
      float s = 0.f;
      #pragma unroll
      for (int jj = 0; jj < 5; ++jj) {
        int nn = HOP * jj + r;
        if (nn < 2048) s += 0.5f - 0.5f * cosf(W_2PI_N * (float)nn);
      }
      v = W_dec[n * 512 + m] / fmaxf(s, 1e-8f);
    }
    b2[idx] = f2bf(v);
  }
}

// ---------------- shared MFMA core (128x128 tile, 4 waves, 2x2 wavegrid) ----------------
// C[ra,rb] = sum_k sA[ra][k]*sB[rb][k]; XOR chunk swizzle both sides.
__device__ __forceinline__ void mfma_tile(const u16* sA, const u16* sB, f32x4 acc[4][4],
                                          int lane, int wr, int wc) {
  const int lr = lane & 15;
  const int hi = lane >> 4;
  #pragma unroll
  for (int ks = 0; ks < 2; ++ks) {
    const int off = (((ks * 4 + hi) ^ (lr & 7)) << 3);
    short8 af[4], bg[4];
    #pragma unroll
    for (int f = 0; f < 4; ++f)
      af[f] = *(const short8*)(sA + (wr + f * 16 + lr) * 64 + off);
    #pragma unroll
    for (int f = 0; f < 4; ++f)
      bg[f] = *(const short8*)(sB + (wc + f * 16 + lr) * 64 + off);
    #pragma unroll
    for (int mf = 0; mf < 4; ++mf)
      #pragma unroll
      for (int nf = 0; nf < 4; ++nf)
        acc[mf][nf] = __builtin_amdgcn_mfma_f32_16x16x32_bf16(af[mf], bg[nf], acc[mf][nf], 0, 0, 0);
  }
}

// ---------------- composite-operator GEMM: C_all[j][r][k1] = sum_m b2[r,512j+m]*wh2t[k1,m] ----------------
__global__ __launch_bounds__(256, 2)
void ccomp_gemm(const u16* __restrict__ b2, const u16* __restrict__ wh2t,
                u16* __restrict__ c_all) {
  __shared__ u16 sA[128 * 64];
  __shared__ u16 sB[128 * 64];
  const int tid = threadIdx.x;
  const int lane = tid & 63;
  const int w = tid >> 6;
  const int m0 = blockIdx.x * 128;      // r rows (512 total)
  const int n0 = blockIdx.y * 128;      // k1 cols (2240, 18 tiles)
  const int jj = blockIdx.z;            // tap 0..4
  const int colsw = (((lane & 7) ^ ((lane >> 3) & 7)) << 3);

  const u16* bsrc[4];
  const u16* asrc[4];
  #pragma unroll
  for (int i = 0; i < 4; ++i) {
    int row = (i * 4 + w) * 8 + (lane >> 3);
    asrc[i] = b2 + (size_t)(m0 + row) * 2560 + 512 * jj + colsw;
    int r2 = n0 + row; if (r2 > 2239) r2 = 2239;
    bsrc[i] = wh2t + (size_t)r2 * 512 + colsw;
  }

  f32x4 acc[4][4];
  #pragma unroll
  for (int a = 0; a < 4; ++a)
    #pragma unroll
    for (int b = 0; b < 4; ++b) acc[a][b] = f32x4{0.f, 0.f, 0.f, 0.f};

  const int wr = (w >> 1) * 64, wc = (w & 1) * 64;

  for (int kc = 0; kc < 512; kc += 64) {
    __syncthreads();
    #pragma unroll
    for (int i = 0; i < 4; ++i)
      gload16(bsrc[i] + kc, &sB[(i * 4 + w) * 512]);
    #pragma unroll
    for (int i = 0; i < 4; ++i)
      gload16(asrc[i] + kc, &sA[(i * 4 + w) * 512]);
    __syncthreads();
    mfma_tile(sA, sB, acc, lane, wr, wc);
  }

  #pragma unroll
  for (int mf = 0; mf < 4; ++mf) {
    #pragma unroll
    for (int e = 0; e < 4; ++e) {
      int rg = m0 + wr + mf * 16 + ((lane >> 4) << 2) + e;   // r < 512 always
      #pragma unroll
      for (int nf = 0; nf < 4; ++nf) {
        int cg = n0 + wc + nf * 16 + (lane & 15);
        if (cg < 2240)
          c_all[(size_t)jj * 1146880 + (size_t)rg * 2240 + cg] = f2bf(acc[mf][nf][e]);
      }
    }
  }
}

// ---------------- fold overlapping tap windows: Ccomp[r][u] = sum_j C_all[j][r][u-(4-j)*448] ----------------
__global__ void ccfold(const u16* __restrict__ c_all, u16* __restrict__ ccomp) {
  int stride = gridDim.x * blockDim.x;
  for (int idx = blockIdx.x * blockDim.x + threadIdx.x; idx < 512 * KC; idx += stride) {
    int r = idx / KC;
    int u = idx - r * KC;
    float s = 0.f;
    #pragma unroll
    for (int j = 0; j < 5; ++j) {
      int k1 = u - (4 - j) * 448;
      if (k1 >= 0 && k1 < K1E)
        s += bf2f(c_all[(size_t)j * 1146880 + (size_t)r * 2240 + k1]);
    }
    ccomp[idx] = f2bf(s);
  }
}

// ---------------- mini-enc: featE[64][512] for the 8 edge frames per bc ----------------
__global__ __launch_bounds__(256, 2)
void enc_mini(const u16* __restrict__ xbe, const u16* __restrict__ wh2,
              u16* __restrict__ featE) {
  __shared__ u16 sA[128 * 64];
  __shared__ u16 sB[128 * 64];
  const int tid = threadIdx.x;
  const int lane = tid & 63;
  const int w = tid >> 6;
  const int n0 = blockIdx.y * 128;
  const int colsw = (((lane & 7) ^ ((lane >> 3) & 7)) << 3);

  const u16* bsrc[4];
  const u16* asrc[4];
  #pragma unroll
  for (int i = 0; i < 4; ++i) {
    int row = (i * 4 + w) * 8 + (lane >> 3);
    bsrc[i] = wh2 + (size_t)(n0 + row) * K1E + colsw;
    int rgc = row < 64 ? row : 63;
    int bci = rgc >> 3;
    int f = rgc & 7;
    int t = (f < 4) ? f : (2993 + f);    // {0,1,2,3,2997,2998,2999,3000}
    asrc[i] = xbe + (size_t)bci * (NBE * RPAD) + (size_t)(t + 4) * RPAD + colsw;
  }

  f32x4 acc[4][4];
  #pragma unroll
  for (int a = 0; a < 4; ++a)
    #pragma unroll
    for (int b = 0; b < 4; ++b) acc[a][b] = f32x4{0.f, 0.f, 0.f, 0.f};

  const int wr = (w >> 1) * 64, wc = (w & 1) * 64;

  for (int kc = 0; kc < K1E; kc += 64) {
    __syncthreads();
    #pragma unroll
    for (int i = 0; i < 4; ++i)
      gload16(bsrc[i] + kc, &sB[(i * 4 + w) * 512]);
    #pragma unroll
    for (int i = 0; i < 4; ++i)
      gload16(asrc[i] + kc, &sA[(i * 4 + w) * 512]);
    __syncthreads();
    mfma_tile(sA, sB, acc, lane, wr, wc);
  }

  #pragma unroll
  for (int mf = 0; mf < 4; ++mf) {
    #pragma unroll
    for (int e = 0; e < 4; ++e) {
      int rg = wr + mf * 16 + ((lane >> 4) << 2) + e;
      if (rg < 64) {
        #pragma unroll
        for (int nf = 0; nf < 4; ++nf) {
          int cg = n0 + wc + nf * 16 + (lane & 15);
          featE[(size_t)rg * 512 + cg] = f2bf(acc[mf][nf][e]);
        }
      }
    }
  }
}

// ---------------- edge combine: exact dec for qi in {0,1,2999,3000} ----------------
__global__ void edge2(const u16* __restrict__ featE, const u16* __restrict__ b2,
                      float* __restrict__ edge_vals) {
  int idx = blockIdx.x * blockDim.x + threadIdx.x;
  if (idx >= 448 * 32) return;
  int r = idx >> 5;
  int row = idx & 31;
  int bci = row >> 2, qe = row & 3;
  int qi = (qe < 2) ? qe : (2997 + qe);  // {0,1,2999,3000}
  float acc = 0.f;
  for (int j = 0; j < 5; ++j) {
    int t = qi + 2 - j;
    if (t >= 0 && t <= 3000) {
      int f = (t < 4) ? t : (t - 2993);
      const u16* bp = b2 + (size_t)r * 2560 + 512 * j;
      const u16* fp = featE + (size_t)(bci * 8 + f) * 512;
      float s = 0.f;
      #pragma unroll 8
      for (int m = 0; m < 512; ++m) s += bf2f(bp[m]) * bf2f(fp[m]);
      acc += s;
    }
  }
  float sf = 0.f, se = 0.f;
  #pragma unroll
  for (int j = 0; j < 5; ++j) {
    int n = HOP * j + r;
    float h = (r < HOP && n < 2048) ? (0.5f - 0.5f * cosf(W_2PI_N * (float)n)) : 0.f;
    sf += h;
    int t = qi + 2 - j;
    if (t >= 0 && t <= 3000) se += h;
  }
  edge_vals[row * 448 + r] = (r < HOP) ? acc * sf / fmaxf(se, 1e-8f) : 0.f;
}

// ---------------- main composite GEMM: out rows qi in [2,2998] (pure-store epilogue) ----------------
__global__ __launch_bounds__(256, 2)
void gemm_main(const u16* __restrict__ xbe, const u16* __restrict__ ccomp,
               float* __restrict__ out) {
  __shared__ u16 sA[128 * 64];
  __shared__ u16 sB[128 * 64];
  const int tid = threadIdx.x;
  const int lane = tid & 63;
  const int w = tid >> 6;
  const int m0 = blockIdx.x * 128;
  const int n0 = blockIdx.y * 128;
  const int colsw = (((lane & 7) ^ ((lane >> 3) & 7)) << 3);

  const u16* bsrc[4];
  const u16* asrc[4];
  #pragma unroll
  for (int i = 0; i < 4; ++i) {
    int row = (i * 4 + w) * 8 + (lane >> 3);
    bsrc[i] = ccomp + (size_t)(n0 + row) * KC + colsw;
    int rg = m0 + row;
    int rgc = rg < M_ROWS ? rg : (M_ROWS - 1);
    int bc = rgc / T_FR;
    int qi = rgc - bc * T_FR;
    asrc[i] = xbe + (size_t)bc * (NBE * RPAD) + (size_t)(qi + 2) * RPAD + colsw;
  }

  f32x4 acc[4][4];
  #pragma unroll
  for (int a = 0; a < 4; ++a)
    #pragma unroll
    for (int b = 0; b < 4; ++b) acc[a][b] = f32x4{0.f, 0.f, 0.f, 0.f};

  const int wr = (w >> 1) * 64, wc = (w & 1) * 64;

  for (int kc = 0; kc < KC; kc += 64) {
    __syncthreads();
    #pragma unroll
    for (int i = 0; i < 4; ++i)
      gload16(bsrc[i] + kc, &sB[(i * 4 + w) * 512]);
    #pragma unroll
    for (int i = 0; i < 4; ++i)
      gload16(asrc[i] + kc, &sA[(i * 4 + w) * 512]);
    __syncthreads();
    mfma_tile(sA, sB, acc, lane, wr, wc);
  }

  // epilogue: interior rows only (edge rows owned by edge_scatter); no oi bounds needed.
  const int lr16 = lane & 15;
  #pragma unroll
  for (int mf = 0; mf < 4; ++mf) {
    #pragma unroll
    for (int e = 0; e < 4; ++e) {
      int rg = m0 + wr + mf * 16 + ((lane >> 4) << 2) + e;
      if (rg < M_ROWS) {
        int bc = rg / T_FR;
        int qi = rg - bc * T_FR;
        if (qi >= 2 && qi <= 2998) {
          int ib = HOP * qi - 142;
          #pragma unroll
          for (int nf = 0; nf < 4; ++nf) {
            int cg = n0 + wc + nf * 16 + lr16;
            if (cg < HOP)
              out[(size_t)bc * L_IN + ib + cg] = acc[mf][nf][e];
          }
        }
      }
    }
  }
}

// ---------------- scatter edge rows into out ----------------
__global__ void edge_scatter(const float* __restrict__ edge_vals, float* __restrict__ out) {
  int idx = blockIdx.x * blockDim.x + threadIdx.x;
  if (idx >= 32 * 441) return;
  int row = idx / 441;
  int r = idx - row * 441;
  int bci = row >> 2, qe = row & 3;
  int qi = (qe < 2) ? qe : (2997 + qe);
  int oi = HOP * qi + r - 142;
  if (oi >= 0 && oi < L_IN)
    out[(size_t)bci * L_IN + oi] = edge_vals[row * 448 + r];
}

// ---------------- launch ----------------

extern "C" void kernel_launch(void* const* d_in, const int* in_sizes, int n_in,
                              void* d_out, int out_size, void* d_ws, size_t ws_size,
                              hipStream_t stream) {
  const float* x     = (const float*)d_in[0];
  const float* W_enc = (const float*)d_in[1];
  const float* W_dec = (const float*)d_in[2];
  float* out = (float*)d_out;
  char* ws = (char*)d_ws;
  char* dob = (char*)d_out;

  // ws layout (25,870,336 B < proven 29.5 MB)
  u16*   xbe   = (u16*)  (ws + 0);            // 8*3016*448*2 = 21,618,688
  u16*   ccomp = (u16*)  (ws + 21618688);     // 512*4032*2   =  4,128,768
  u16*   featE = (u16*)  (ws + 25747456);     // 64*512*2     =     65,536
  float* evals = (float*)(ws + 25812992);     // 32*448*4     =     57,344

  // d_out staging (all dead before gemm_main/edge_scatter overwrite d_out)
  u16* wh2t  = (u16*)(dob + 0);               // 2240*512*2   =  2,293,760
  u16* b2    = (u16*)(dob + 2293760);         // 512*2560*2   =  2,621,440
  u16* c_all = (u16*)(dob + 4915200);         // 5*512*2240*2 = 11,468,800
  u16* wh2   = (u16*)(dob + 16384000);        // 512*2240*2   =  2,293,760 (ends 18,677,760)

  prep_all  <<<2048, 256, 0, stream>>>(x, W_enc, W_dec, xbe, wh2, wh2t, b2);
  ccomp_gemm<<<dim3(4, 18, 5), 256, 0, stream>>>(b2, wh2t, c_all);
  ccfold    <<<2048, 256, 0, stream>>>(c_all, ccomp);
  enc_mini  <<<dim3(1, 4), 256, 0, stream>>>(xbe, wh2, featE);
  edge2     <<<56, 256, 0, stream>>>(featE, b2, evals);
  gemm_main <<<dim3(188, 4), 256, 0, stream>>>(xbe, ccomp, out);
  edge_scatter<<<56, 256, 0, stream>>>(evals, out);
}

// Round 14
// 153.399 us; speedup vs baseline: 1.5714x; 1.5714x over previous
//
#include <hip/hip_runtime.h>
#include <stdint.h>

typedef unsigned short u16;
typedef unsigned int u32;
typedef __attribute__((ext_vector_type(8))) short short8;
typedef __attribute__((ext_vector_type(4))) float f32x4;

#define L_IN   1323000
#define PAD    1024
#define HOP    441
#define T_FR   3001         // frames per (b,c) row
#define M_ROWS 24008        // 8 * 3001
#define NB     3008         // xb rows per bc (need 3005)
#define RPAD   448          // padded block row length (441 -> 448, 16B-aligned bf16 rows)
#define K1E    2240         // enc K: 5 taps * 448
#define K2     2560         // dec K: 5 taps * 512
#define W_2PI_N 3.0679615757712823e-3f   // 2*pi/2048

__device__ __forceinline__ u16 f2bf(float f) {
  union { float f; u32 u; } v; v.f = f;
  u32 r = v.u + 0x7FFFu + ((v.u >> 16) & 1u);   // RNE
  return (u16)(r >> 16);
}

__device__ __forceinline__ void gload16(const void* g, void* l) {
  __builtin_amdgcn_global_load_lds(
      (const __attribute__((address_space(1))) u32*)g,
      (__attribute__((address_space(3))) u32*)l, 16, 0, 0);
}

// XCD-aware bijective swizzle for enc: 752 tiles = 8 XCDs x 94; n-fastest within chunk.
__device__ __forceinline__ void tile_from_bid(int bid, int& m0, int& n0) {
  int g = (bid & 7) * 94 + (bid >> 3);
  m0 = (g >> 2) * 128;
  n0 = (g & 3) * 128;
}

// ---------------- prep: blocked bf16 x, folded/rearranged weights ----------------
// xb[bc, u, r] = bf16(x_reflect[441u + r - 1024]), rows padded to 448
// wh2[m, 448j + r] = bf16(hann[441j+r] * W_enc[m, 441j+r])  (0 where r>=441 or n>=2048)
// b2[r, 512j + m]  = bf16(W_dec[441j+r, m])                 (0 where r>=441 or n>=2048)
__global__ void prep_all(const float* __restrict__ x,
                         const float* __restrict__ W_enc, const float* __restrict__ W_dec,
                         u16* __restrict__ xb, u16* __restrict__ wh2,
                         u16* __restrict__ b2, float* __restrict__ zeros) {
  int stride = gridDim.x * blockDim.x;
  int tid0 = blockIdx.x * blockDim.x + threadIdx.x;
  for (int idx = tid0; idx < 64; idx += stride) zeros[idx] = 0.f;
  for (int idx = tid0; idx < 8 * NB * RPAD; idx += stride) {
    int bc = idx / (NB * RPAD);
    int rem = idx - bc * (NB * RPAD);
    int u = rem / RPAD;
    int r = rem - u * RPAD;
    int s = HOP * u + r - PAD;
    int ja = s < 0 ? -s : s;
    int jb = 2 * L_IN - 2 - ja;
    int jr = ja < jb ? ja : jb;          // reflect (no edge repeat)
    xb[idx] = f2bf(x[(size_t)bc * L_IN + jr]);
  }
  for (int idx = tid0; idx < 512 * K1E; idx += stride) {
    int m = idx / K1E;
    int k = idx - m * K1E;
    int j = k / RPAD;
    int r = k - j * RPAD;
    int n = HOP * j + r;
    float v = 0.f;
    if (r < HOP && n < 2048)
      v = (0.5f - 0.5f * cosf(W_2PI_N * (float)n)) * W_enc[m * 2048 + n];
    wh2[idx] = f2bf(v);
  }
  for (int idx = tid0; idx < 512 * K2; idx += stride) {
    int r = idx / K2;
    int k = idx - r * K2;
    int j = k >> 9;
    int m = k & 511;
    int n = HOP * j + r;
    float v = (r < HOP && n < 2048) ? W_dec[n * 512 + m] : 0.f;
    b2[idx] = f2bf(v);
  }
}

// ---------------- shared MFMA core (128x128 tile, 4 waves, 2x2 wavegrid) ----------------
// LDS chunk (row, c) holds global chunk c ^ (row&7)  (staged via pre-swizzled source);
// reader wants global chunk ks*4+hi of row R -> reads LDS chunk (ks*4+hi) ^ (R&7).
__device__ __forceinline__ void mfma_tile(const u16* sA, const u16* sB, f32x4 acc[4][4],
                                          int lane, int wr, int wc) {
  const int lr = lane & 15;
  const int hi = lane >> 4;
  #pragma unroll
  for (int ks = 0; ks < 2; ++ks) {
    const int off = (((ks * 4 + hi) ^ (lr & 7)) << 3);   // swizzled chunk, u16 elements
    short8 af[4], bg[4];
    #pragma unroll
    for (int f = 0; f < 4; ++f)
      af[f] = *(const short8*)(sA + (wr + f * 16 + lr) * 64 + off);
    #pragma unroll
    for (int f = 0; f < 4; ++f)
      bg[f] = *(const short8*)(sB + (wc + f * 16 + lr) * 64 + off);
    #pragma unroll
    for (int mf = 0; mf < 4; ++mf)
      #pragma unroll
      for (int nf = 0; nf < 4; ++nf)
        acc[mf][nf] = __builtin_amdgcn_mfma_f32_16x16x32_bf16(af[mf], bg[nf], acc[mf][nf], 0, 0, 0);
  }
}

// ---------------- GEMM1: feat[24008,512] = xb-frames @ wh2^T ----------------
// Plain GEMM with A-row stride 448 (448-padding collapses the 5-tap im2col).
// XCD-swizzled 1D grid: wh2 L2-resident per XCD (measured best for enc).

__global__ __launch_bounds__(256, 2)
void gemm_enc(const u16* __restrict__ xb, const u16* __restrict__ wh2,
              u16* __restrict__ featb) {
  __shared__ u16 sA[128 * 64];
  __shared__ u16 sB[128 * 64];
  const int tid = threadIdx.x;
  const int lane = tid & 63;
  const int w = tid >> 6;
  int m0, n0;
  tile_from_bid(blockIdx.x, m0, n0);
  const int colsw = (((lane & 7) ^ ((lane >> 3) & 7)) << 3);  // pre-swizzled source chunk

  const u16* bsrc[4];
  const u16* asrc[4];
  #pragma unroll
  for (int i = 0; i < 4; ++i) {
    int row = (i * 4 + w) * 8 + (lane >> 3);
    bsrc[i] = wh2 + (size_t)(n0 + row) * K1E + colsw;
    int rg = m0 + row;
    int rgc = rg < M_ROWS ? rg : (M_ROWS - 1);
    int bc = rgc / T_FR;
    int t  = rgc - bc * T_FR;
    asrc[i] = xb + ((size_t)bc * NB + t) * RPAD + colsw;
  }

  f32x4 acc[4][4];
  #pragma unroll
  for (int a = 0; a < 4; ++a)
    #pragma unroll
    for (int b = 0; b < 4; ++b) acc[a][b] = f32x4{0.f, 0.f, 0.f, 0.f};

  const int wr = (w >> 1) * 64, wc = (w & 1) * 64;

  for (int kc = 0; kc < K1E; kc += 64) {
    __syncthreads();
    #pragma unroll
    for (int i = 0; i < 4; ++i)
      gload16(bsrc[i] + kc, &sB[(i * 4 + w) * 512]);
    #pragma unroll
    for (int i = 0; i < 4; ++i)
      gload16(asrc[i] + kc, &sA[(i * 4 + w) * 512]);
    __syncthreads();
    mfma_tile(sA, sB, acc, lane, wr, wc);
  }

  #pragma unroll
  for (int mf = 0; mf < 4; ++mf) {
    #pragma unroll
    for (int e = 0; e < 4; ++e) {
      int rg = m0 + wr + mf * 16 + ((lane >> 4) << 2) + e;
      if (rg < M_ROWS) {
        #pragma unroll
        for (int nf = 0; nf < 4; ++nf) {
          int cg = n0 + wc + nf * 16 + (lane & 15);
          featb[(size_t)rg * 512 + cg] = f2bf(acc[mf][nf][e]);
        }
      }
    }
  }
}

// ---------------- GEMM2: decode + overlap-add (im2col over 5 taps), fused epilogue ----------------
// n-FASTEST grid (4,188): the 4 n-tiles of each m-tile are dispatch-adjacent, sharing
// the 135KB featb panel in L2; b2 (2.6MB) stays globally hot. Predicted FETCH ~35MB.

__global__ __launch_bounds__(256, 2)
void gemm_dec(const u16* __restrict__ featb, const u16* __restrict__ b2,
              const u16* __restrict__ zeros, float* __restrict__ out) {
  __shared__ u16 sA[128 * 64];
  __shared__ u16 sB[128 * 64];
  const int tid = threadIdx.x;
  const int lane = tid & 63;
  const int w = tid >> 6;
  const int m0 = blockIdx.y * 128;
  const int n0 = blockIdx.x * 128;
  const int colsw = (((lane & 7) ^ ((lane >> 3) & 7)) << 3);

  const u16* bsrc[4];
  const u16* fsrc[4];
  int qiv[4];
  unsigned vmask = 0;
  #pragma unroll
  for (int i = 0; i < 4; ++i) {
    int row = (i * 4 + w) * 8 + (lane >> 3);
    bsrc[i] = b2 + (size_t)(n0 + row) * K2 + colsw;
    int rg = m0 + row;
    int rgc = rg < M_ROWS ? rg : (M_ROWS - 1);
    int bc = rgc / T_FR;
    int qi = rgc - bc * T_FR;
    if (rg < M_ROWS) vmask |= 1u << i;
    qiv[i] = qi;
    fsrc[i] = featb + (size_t)(bc * T_FR + qi + 2) * 512 + colsw;
  }

  f32x4 acc[4][4];
  #pragma unroll
  for (int a = 0; a < 4; ++a)
    #pragma unroll
    for (int b = 0; b < 4; ++b) acc[a][b] = f32x4{0.f, 0.f, 0.f, 0.f};

  const int wr = (w >> 1) * 64, wc = (w & 1) * 64;

  for (int kc = 0; kc < K2; kc += 64) {
    int jt = kc >> 9;                 // tap index 0..4 (BK=64 never straddles a tap)
    __syncthreads();
    #pragma unroll
    for (int i = 0; i < 4; ++i)
      gload16(bsrc[i] + kc, &sB[(i * 4 + w) * 512]);
    #pragma unroll
    for (int i = 0; i < 4; ++i) {
      int t = qiv[i] + 2 - jt;
      bool ok = ((vmask >> i) & 1) && (t >= 0) && (t <= 3000);
      const u16* pa = ok ? (fsrc[i] + kc - 1024 * jt) : (zeros + colsw);
      gload16(pa, &sA[(i * 4 + w) * 512]);
    }
    __syncthreads();
    mfma_tile(sA, sB, acc, lane, wr, wc);
  }

  // epilogue: (bc,qi,r) -> out index i = 441*qi + r - 142, scaled by 1/win_norm.
  const int lr16 = lane & 15;
  float hh[4][5];
  float rnfull[4];
  int cgv[4];
  #pragma unroll
  for (int nf = 0; nf < 4; ++nf) {
    int cg = n0 + wc + nf * 16 + lr16;
    cgv[nf] = cg;
    float s = 0.f;
    #pragma unroll
    for (int j = 0; j < 5; ++j) {
      int n = HOP * j + cg;
      float h = (cg < HOP && n < 2048) ? (0.5f - 0.5f * cosf(W_2PI_N * (float)n)) : 0.f;
      hh[nf][j] = h;
      s += h;
    }
    rnfull[nf] = 1.f / fmaxf(s, 1e-8f);
  }

  #pragma unroll
  for (int mf = 0; mf < 4; ++mf) {
    #pragma unroll
    for (int e = 0; e < 4; ++e) {
      int rg = m0 + wr + mf * 16 + ((lane >> 4) << 2) + e;
      if (rg < M_ROWS) {
        int bc = rg / T_FR;
        int qi = rg - bc * T_FR;
        int ib = HOP * qi - 142;
        bool interior = (qi >= 2) && (qi <= 2998);
        #pragma unroll
        for (int nf = 0; nf < 4; ++nf) {
          if (cgv[nf] < HOP) {
            int oi = ib + cgv[nf];
            if (oi >= 0 && oi < L_IN) {
              float rn;
              if (interior) {
                rn = rnfull[nf];
              } else {
                float s = 0.f;
                #pragma unroll
                for (int j = 0; j < 5; ++j)
                  if ((unsigned)(qi + 2 - j) <= 3000u) s += hh[nf][j];
                rn = 1.f / fmaxf(s, 1e-8f);
              }
              out[(size_t)bc * L_IN + oi] = acc[mf][nf][e] * rn;
            }
          }
        }
      }
    }
  }
}

// ---------------- launch ----------------

extern "C" void kernel_launch(void* const* d_in, const int* in_sizes, int n_in,
                              void* d_out, int out_size, void* d_ws, size_t ws_size,
                              hipStream_t stream) {
  const float* x     = (const float*)d_in[0];
  const float* W_enc = (const float*)d_in[1];
  const float* W_dec = (const float*)d_in[2];
  float* out = (float*)d_out;
  char* ws = (char*)d_ws;

  // xb lives in d_out (21,561,344 B < 42,336,000 B): written by prep, read by enc,
  // then gemm_dec's epilogue bijectively overwrites every d_out element last.
  u16* xb = (u16*)d_out;

  // workspace layout (total 29,499,648 B ~= 28.1 MiB)
  u16*   wh2   = (u16*)  (ws + 0);            // 512*2240*2  =  2,293,760
  u16*   b2    = (u16*)  (ws + 2293760);      // 512*2560*2  =  2,621,440
  u16*   featb = (u16*)  (ws + 4915200);      // 24008*512*2 = 24,584,192
  float* zeros = (float*)(ws + 29499392);     // 256 B zero block (gather redirect)

  prep_all<<<2048, 256, 0, stream>>>(x, W_enc, W_dec, xb, wh2, b2, zeros);
  gemm_enc<<<752, 256, 0, stream>>>(xb, wh2, featb);
  gemm_dec<<<dim3(4, 188), 256, 0, stream>>>(featb, b2, (const u16*)zeros, out);
}